// Round 8
// baseline (71.153 us; speedup 1.0000x reference)
//
#include <hip/hip_runtime.h>

#define IMG 512
#define OUT_N 502
#define NPLANE 48
#define STRIPS 32            // 16 output rows per strip
#define SROWS 16
#define C1c 0.0001f
#define C2c 0.0004f
#define EODD 264             // odd-col region offset (float4 units) in row buffer

// ssim from H-blurred (Bs, Bd, BP, BM) where s=x+y, d=x-y:
// mux = (Bs+Bd)/2, muy = (Bs-Bd)/2 (linearity); P=blur(s^2), M=blur(d^2).
__device__ __forceinline__ float ssim_px(float Bs, float Bd, float BP, float BM) {
    float mx = 0.5f*(Bs + Bd), my = 0.5f*(Bs - Bd);
    float A = mx*mx, B = my*my, mxy = mx*my;
    float sumsq = 0.5f*(BP + BM) - A - B;   // sigx2 + sigy2
    float sxy   = 0.25f*(BP - BM) - mxy;    // sigxy
    float num = (2.f*mxy + C1c) * (2.f*sxy + C2c);
    float den = (A + B + C1c) * (sumsq + C2c);
    return num / den;
}

// 512 threads, 1 col/thread. V-blur in a 12-row (s,d) float2 ring (24 VGPR,
// static idx); squares recomputed per tap, shared by the row pair. H-pass:
// 2 rows x 256 threads x 2 cols from parity-split LDS row buffers.
// __launch_bounds__(512,4): VGPR cap 64 -> 8 waves/SIMD -> 4 blocks/CU.
__global__ __launch_bounds__(512, 4) void ssim_strip(
    const float* __restrict__ in, const float* __restrict__ tgt,
    const float* __restrict__ w, float* __restrict__ partial)
{
    __shared__ float4 buf[2][2][528];   // [pair parity][row in pair][parity col]
    __shared__ float g1s[16];
    __shared__ float red[8];

    const int tid   = threadIdx.x;
    const int strip = blockIdx.x;
    const int plane = blockIdx.y;
    const int r0 = strip * SROWS;
    const float* __restrict__ ip = in  + (size_t)plane * (IMG*IMG);
    const float* __restrict__ tp = tgt + (size_t)plane * (IMG*IMG);

    // 1D factor = row sums of 2D kernel (exact: w2d = outer(g,g), sum g = 1)
    if (tid < 11) {
        float s = 0.f;
        #pragma unroll
        for (int j = 0; j < 11; ++j) s += w[tid*11 + j];
        g1s[tid] = s;
    }
    __syncthreads();
    float g[11];
    #pragma unroll
    for (int j = 0; j < 11; ++j)
        g[j] = __int_as_float(__builtin_amdgcn_readfirstlane(__float_as_int(g1s[j])));

    float2 ring[12];                    // pair slot p%6 -> entries 2p, 2p+1
    float acc = 0.f;
    const int wcol = (tid >> 1) + (tid & 1) * EODD;   // V-write slot for col tid
    const int hrow = tid >> 8;                        // H: row within pair
    const int ht   = tid & 255;                       // H: col-pair index
    const int c0   = 2 * ht;

#define LOADP(P) \
    float x0=0.f,y0=0.f,x1=0.f,y1=0.f; \
    { const int ra = r0 + 2*(P); \
      if (ra < IMG)     { x0 = ip[ra*IMG + tid];     y0 = tp[ra*IMG + tid]; } \
      if (ra + 1 < IMG) { x1 = ip[(ra+1)*IMG + tid]; y1 = tp[(ra+1)*IMG + tid]; } }

#define INSP(SP) \
    ring[2*(SP)  ] = make_float2(x0 + y0, x0 - y0); \
    ring[2*(SP)+1] = make_float2(x1 + y1, x1 - y1);

    // V-blur pair T: out rows 2T (taps j=0..10, g[j]) and 2T+1 (j=1..11, g[j-1]).
    // Row 2T+j lives at ring[2*((T+(j>>1))%6) + (j&1)]. s2/d2 shared by both rows.
#define VBLUR(T) \
    float v0s=0,v0d=0,v0P=0,v0M=0, v1s=0,v1d=0,v1P=0,v1M=0; \
    _Pragma("unroll") \
    for (int j = 0; j <= 11; ++j) { \
        float2 sd = ring[2*(((T) + (j>>1)) % 6) + (j&1)]; \
        float s2 = sd.x*sd.x, d2 = sd.y*sd.y; \
        if (j <= 10) { float wj = g[j];   v0s += wj*sd.x; v0d += wj*sd.y; v0P += wj*s2; v0M += wj*d2; } \
        if (j >= 1)  { float wj = g[j-1]; v1s += wj*sd.x; v1d += wj*sd.y; v1P += wj*s2; v1M += wj*d2; } \
    }

#define HPASS(T) \
    { const int oy = r0 + 2*(T) + hrow; \
      if (oy < OUT_N && c0 < OUT_N) { \
        float A0=0,A1=0,A2=0,A3=0,B0=0,B1=0,B2=0,B3=0; \
        _Pragma("unroll") \
        for (int j = 0; j < 12; ++j) { \
            float4 v = buf[(T)&1][hrow][ht + (j>>1) + (j&1)*EODD]; \
            if (j <= 10) { float wj=g[j];   A0+=wj*v.x; A1+=wj*v.y; A2+=wj*v.z; A3+=wj*v.w; } \
            if (j >= 1)  { float wj=g[j-1]; B0+=wj*v.x; B1+=wj*v.y; B2+=wj*v.z; B3+=wj*v.w; } \
        } \
        acc += ssim_px(A0,A1,A2,A3); \
        acc += ssim_px(B0,B1,B2,B3); \
      } }

    // Iter T: prefetch pair T+6 (loads hidden under V-blur), V-blur pair T from
    // ring (pairs T..T+5 = slots T%6..(T+5)%6), write LDS, insert prefetched
    // pair into slot T%6 (just vacated), barrier, H-pass pair T.
#define ITER(T, LD) \
    { LOADP((LD) ? (T)+6 : (T)+6)                                   \
      if (!(LD)) { x0=0.f; y0=0.f; x1=0.f; y1=0.f; }                \
      VBLUR(T)                                                      \
      buf[(T)&1][0][wcol] = make_float4(v0s, v0d, v0P, v0M);        \
      buf[(T)&1][1][wcol] = make_float4(v1s, v1d, v1P, v1M);        \
      INSP((T)%6)                                                   \
      __syncthreads();                                              \
      HPASS(T)                                                      \
    }

    // Prologue: fill ring with pairs 0..5 (rows 0..11)
    { LOADP(0) INSP(0) }  { LOADP(1) INSP(1) }  { LOADP(2) INSP(2) }
    { LOADP(3) INSP(3) }  { LOADP(4) INSP(4) }  { LOADP(5) INSP(5) }

    // Main: 8 pair-iterations -> 16 output rows. Pair 12 (rows 24,25) is the
    // last real load; iter 7's prefetch (pair 13) is OOB-masked to zeros.
    ITER(0,1) ITER(1,1) ITER(2,1) ITER(3,1)
    ITER(4,1) ITER(5,1) ITER(6,1) ITER(7,0)

    // block reduction: wave shuffle, then 8 wave-partials through LDS
    #pragma unroll
    for (int off = 32; off > 0; off >>= 1)
        acc += __shfl_down(acc, off, 64);
    const int lane = tid & 63, wv = tid >> 6;
    if (lane == 0) red[wv] = acc;
    __syncthreads();
    if (tid == 0) {
        float t = 0.f;
        #pragma unroll
        for (int i = 0; i < 8; ++i) t += red[i];
        partial[plane * STRIPS + strip] = t;
    }
}

// Deterministic final reduction: fixed traversal, double accumulation.
__global__ __launch_bounds__(256) void ssim_final(
    const float* __restrict__ partial, int n, float* __restrict__ out)
{
    __shared__ double red[256];
    double s = 0.0;
    for (int i = threadIdx.x; i < n; i += 256) s += (double)partial[i];
    red[threadIdx.x] = s;
    __syncthreads();
    for (int off = 128; off > 0; off >>= 1) {
        if (threadIdx.x < off) red[threadIdx.x] += red[threadIdx.x + off];
        __syncthreads();
    }
    if (threadIdx.x == 0) out[0] = (float)(1.0 - red[0] / (double)NPLANE);
}

extern "C" void kernel_launch(void* const* d_in, const int* in_sizes, int n_in,
                              void* d_out, int out_size, void* d_ws, size_t ws_size,
                              hipStream_t stream) {
    const float* in  = (const float*)d_in[0];
    const float* tgt = (const float*)d_in[1];
    const float* wt  = (const float*)d_in[2];
    float* out  = (float*)d_out;
    float* part = (float*)d_ws;

    dim3 grid(STRIPS, NPLANE);   // 32 row-strips x 48 planes = 1536 blocks
    ssim_strip<<<grid, 512, 0, stream>>>(in, tgt, wt, part);
    ssim_final<<<1, 256, 0, stream>>>(part, STRIPS * NPLANE, out);
}

// Round 9
// 58.371 us; speedup vs baseline: 1.2190x; 1.2190x over previous
//
#include <hip/hip_runtime.h>

#define IMG 512
#define OUT_N 502
#define NPLANE 48
#define SROWS 25             // output rows per strip
#define NSTRIP 21            // ceil(502/25)
#define NITER 36             // = 3 * 12 macro-iterations, zero waste
#define C1c 0.0001f
#define C2c 0.0004f
#define EV_OFF 264   // odd-column sub-block offset (float4 units) in row buffer

__device__ __forceinline__ float ssim_px(float mx, float my, float P, float M) {
    float A = mx*mx, B = my*my, mxy = mx*my;
    float sumsq = 0.5f*(P+M) - A - B;      // sigx2 + sigy2
    float sxy   = 0.25f*(P-M) - mxy;       // sigxy
    float num = (2.f*mxy + C1c) * (2.f*sxy + C2c);
    float den = (A + B + C1c) * (sumsq + C2c);
    return num / den;
}

// Block = full-width 512-col strip, 25 output rows, 256 threads (2 cols/thr).
// Same per-iteration structure as the proven 56us kernel (4-field float4 ring,
// parity-split LDS, 84 VGPR), but the 36 iterations run as 3 passes of a
// 12-iteration macro-body inside a #pragma unroll 1 loop: code ~23KB -> fits
// the 32KB L1I (the fully-unrolled 50-60KB version streams I$ every block and
// pins VALUBusy at 34%). Ring slots/parity stay static because 12 is even and
// kb % 12 == 0. Wave-uniform predicates (k>=11 H, k>=10 V) gate the phases.
__global__ __launch_bounds__(256, 3) void ssim_strip(
    const float* __restrict__ in, const float* __restrict__ tgt,
    const float* __restrict__ w, float* __restrict__ partial)
{
    __shared__ float4 buf[2][528];
    __shared__ float g1s[16];
    __shared__ float red[4];

    const int tid   = threadIdx.x;
    const int strip = blockIdx.x;
    const int plane = blockIdx.y;
    const int r0 = strip * SROWS;
    const float* __restrict__ ip = in  + (size_t)plane * (IMG*IMG);
    const float* __restrict__ tp = tgt + (size_t)plane * (IMG*IMG);

    // 1D factor = row sums of 2D kernel (exact: w2d = outer(g,g), sum g = 1)
    if (tid < 11) {
        float s = 0.f;
        #pragma unroll
        for (int j = 0; j < 11; ++j) s += w[tid*11 + j];
        g1s[tid] = s;
    }
    __syncthreads();
    float g[11];
    #pragma unroll
    for (int j = 0; j < 11; ++j)
        g[j] = __int_as_float(__builtin_amdgcn_readfirstlane(__float_as_int(g1s[j])));

    float4 rA[12], rB[12];     // V-ring: cols tid and tid+256
    float acc = 0.f;
    const int wrA = (tid >> 1) + (tid & 1) * EV_OFF;   // col tid
    const int wrB = wrA + 128;                          // col tid+256

    #pragma unroll 1
    for (int kb = 0; kb < NITER; kb += 12) {
        #pragma unroll
        for (int i = 0; i < 12; ++i) {          // static i -> static ring slots
            const int k = kb + i;               // runtime, wave-uniform

            // ---- load input rows (row-clamped; OOB -> zeros) ----
            float xa = 0.f, ya = 0.f, xb = 0.f, yb = 0.f;
            {
                const int r_ = r0 + k;
                if (r_ < IMG) {
                    const float* ipr = ip + r_ * IMG;
                    const float* tpr = tp + r_ * IMG;
                    xa = ipr[tid];       ya = tpr[tid];
                    xb = ipr[tid + 256]; yb = tpr[tid + 256];
                }
            }

            // ---- H-pass + SSIM for output row r0+k-11 (reads prev V row) ----
            if (k >= 11) {                       // ring-fill gate (uniform)
                const int oy_ = r0 + k - 11;
                if (oy_ < OUT_N) {
                    float A0=0.f,A1=0.f,A2=0.f,A3=0.f,B0=0.f,B1=0.f,B2=0.f,B3=0.f;
                    #pragma unroll
                    for (int j = 0; j < 12; ++j) {
                        float4 v = buf[(i&1)^1][tid + (j>>1) + (j&1)*EV_OFF];
                        if (j <= 10) { float wj=g[j];   A0+=wj*v.x; A1+=wj*v.y; A2+=wj*v.z; A3+=wj*v.w; }
                        if (j >= 1)  { float wj=g[j-1]; B0+=wj*v.x; B1+=wj*v.y; B2+=wj*v.z; B3+=wj*v.w; }
                    }
                    const int c0_ = 2*tid;
                    if (c0_ < OUT_N)     acc += ssim_px(A0,A1,A2,A3);
                    if (c0_ + 1 < OUT_N) acc += ssim_px(B0,B1,B2,B3);
                }
            }

            // ---- ring insert (slot i, static) ----
            { float sa_=xa+ya, da_=xa-ya; rA[i] = make_float4(xa, ya, sa_*sa_, da_*da_); }
            { float sb_=xb+yb, db_=xb-yb; rB[i] = make_float4(xb, yb, sb_*sb_, db_*db_); }

            // ---- V-blur of rows k-10..k -> LDS row buffer buf[i&1] ----
            if (k >= 10) {                       // ring full (uniform)
                float4 va_ = make_float4(0.f,0.f,0.f,0.f);
                float4 vb_ = make_float4(0.f,0.f,0.f,0.f);
                #pragma unroll
                for (int t = 0; t < 11; ++t) {
                    const int sl_ = (i + 2 + t) % 12;   // static (k=i mod 12)
                    float wj = g[t];
                    va_.x += wj*rA[sl_].x; va_.y += wj*rA[sl_].y;
                    va_.z += wj*rA[sl_].z; va_.w += wj*rA[sl_].w;
                    vb_.x += wj*rB[sl_].x; vb_.y += wj*rB[sl_].y;
                    vb_.z += wj*rB[sl_].z; vb_.w += wj*rB[sl_].w;
                }
                buf[i&1][wrA] = va_;
                buf[i&1][wrB] = vb_;
            }

            __syncthreads();
        }
    }

    // block reduction
    #pragma unroll
    for (int off = 32; off > 0; off >>= 1)
        acc += __shfl_down(acc, off, 64);
    const int lane = tid & 63, wv = tid >> 6;
    if (lane == 0) red[wv] = acc;
    __syncthreads();
    if (tid == 0)
        partial[plane * NSTRIP + strip] = red[0] + red[1] + red[2] + red[3];
}

// Deterministic final reduction: fixed traversal, double accumulation.
__global__ __launch_bounds__(256) void ssim_final(
    const float* __restrict__ partial, int n, float* __restrict__ out)
{
    __shared__ double red[256];
    double s = 0.0;
    for (int i = threadIdx.x; i < n; i += 256) s += (double)partial[i];
    red[threadIdx.x] = s;
    __syncthreads();
    for (int off = 128; off > 0; off >>= 1) {
        if (threadIdx.x < off) red[threadIdx.x] += red[threadIdx.x + off];
        __syncthreads();
    }
    if (threadIdx.x == 0) out[0] = (float)(1.0 - red[0] / (double)NPLANE);
}

extern "C" void kernel_launch(void* const* d_in, const int* in_sizes, int n_in,
                              void* d_out, int out_size, void* d_ws, size_t ws_size,
                              hipStream_t stream) {
    const float* in  = (const float*)d_in[0];
    const float* tgt = (const float*)d_in[1];
    const float* wt  = (const float*)d_in[2];
    float* out  = (float*)d_out;
    float* part = (float*)d_ws;

    dim3 grid(NSTRIP, NPLANE);   // 21 strips x 48 planes = 1008 blocks (~4/CU)
    ssim_strip<<<grid, 256, 0, stream>>>(in, tgt, wt, part);
    ssim_final<<<1, 256, 0, stream>>>(part, NSTRIP * NPLANE, out);
}

// Round 10
// 50.984 us; speedup vs baseline: 1.3956x; 1.1449x over previous
//
#include <hip/hip_runtime.h>

typedef float v2f __attribute__((ext_vector_type(2)));

#define IMG 512
#define OUT_N 502
#define NPLANE 48
#define NSTRIP 16
#define SROWS 32
#define C1c 0.0001f
#define C2c 0.0004f
#define EV_OFF 264   // odd-column sub-block offset (float4 units) in row buffer

__device__ __forceinline__ float ssim_px(float mx, float my, float P, float M) {
    float A = mx*mx, B = my*my, mxy = mx*my;
    float sumsq = 0.5f*(P+M) - A - B;      // sigx2 + sigy2
    float sxy   = 0.25f*(P-M) - mxy;       // sigxy
    float num = (2.f*mxy + C1c) * (2.f*sxy + C2c);
    float den = (A + B + C1c) * (sumsq + C2c);
    return num / den;
}

// Block = 512-col strip, 32 output rows, 256 threads (2 cols/thread).
// vs the 56us R3 kernel: (1) depth-2 register prefetch of input rows, (2) raw
// s_barrier + manual lgkmcnt(0) so counted vmcnt keeps prefetched loads in
// flight across barriers (no __syncthreads vmcnt(0) drain), (3) v2f
// (ext_vector float2) accumulators to get v_pk_fma_f32 packed math.
__global__ __launch_bounds__(256, 2) void ssim_strip(
    const float* __restrict__ in, const float* __restrict__ tgt,
    const float* __restrict__ w, float* __restrict__ partial)
{
    __shared__ float4 buf[2][528];
    __shared__ float g1s[16];
    __shared__ float red[4];

    const int tid   = threadIdx.x;
    const int strip = blockIdx.x;
    const int plane = blockIdx.y;
    const int r0 = strip * SROWS;
    const float* __restrict__ ip = in  + (size_t)plane * (IMG*IMG);
    const float* __restrict__ tp = tgt + (size_t)plane * (IMG*IMG);

    // 1D factor = row sums of 2D kernel (exact: w2d = outer(g,g), sum g = 1)
    if (tid < 11) {
        float s = 0.f;
        #pragma unroll
        for (int j = 0; j < 11; ++j) s += w[tid*11 + j];
        g1s[tid] = s;
    }
    __syncthreads();
    float g[11];
    #pragma unroll
    for (int j = 0; j < 11; ++j)
        g[j] = __int_as_float(__builtin_amdgcn_readfirstlane(__float_as_int(g1s[j])));

    // V-ring: 12 rows x {(x,y),(P,M)} x 2 cols, all static-indexed
    v2f rxyA[12], rpmA[12], rxyB[12], rpmB[12];
    // depth-2 prefetch sets (parity = row % 2)
    float pxa[2], pya[2], pxb[2], pyb[2];
    float acc = 0.f;
    const int wrA = (tid >> 1) + (tid & 1) * EV_OFF;   // col tid
    const int wrB = wrA + 128;                          // col tid+256

#define ISSUE(ROW, P) \
    { const int r_ = r0 + (ROW); \
      if (r_ < IMG) { \
        const float* ipr = ip + r_ * IMG; \
        const float* tpr = tp + r_ * IMG; \
        pxa[P] = ipr[tid];       pya[P] = tpr[tid]; \
        pxb[P] = ipr[tid + 256]; pyb[P] = tpr[tid + 256]; \
      } else { pxa[P]=0.f; pya[P]=0.f; pxb[P]=0.f; pyb[P]=0.f; } }

#define ISSUE_G(ROW, P) { if ((ROW) <= 41) ISSUE(ROW, P) }

#define RINGINS(SL, P) \
    { float xa=pxa[P], ya=pya[P], xb=pxb[P], yb=pyb[P]; \
      float sa=xa+ya, da=xa-ya, sb=xb+yb, db=xb-yb; \
      rxyA[SL] = (v2f){xa, ya}; rpmA[SL] = (v2f){sa*sa, da*da}; \
      rxyB[SL] = (v2f){xb, yb}; rpmB[SL] = (v2f){sb*sb, db*db}; }

#define VWR(SL, BP) \
    { v2f vxyA=(v2f)(0.f), vpmA=(v2f)(0.f), vxyB=(v2f)(0.f), vpmB=(v2f)(0.f); \
      _Pragma("unroll") \
      for (int t = 0; t < 11; ++t) { \
        const int sl_ = ((SL) + 2 + t) % 12;   /* rows K-10..K, static */ \
        const float wj = g[t]; \
        vxyA += wj * rxyA[sl_]; vpmA += wj * rpmA[sl_]; \
        vxyB += wj * rxyB[sl_]; vpmB += wj * rpmB[sl_]; \
      } \
      buf[BP][wrA] = make_float4(vxyA.x, vxyA.y, vpmA.x, vpmA.y); \
      buf[BP][wrB] = make_float4(vxyB.x, vxyB.y, vpmB.x, vpmB.y); }

#define HPASS(K) \
    { const int oy_ = r0 + (K) - 11; \
      if (oy_ < OUT_N) { \
        v2f Amu=(v2f)(0.f), Apm=(v2f)(0.f), Bmu=(v2f)(0.f), Bpm=(v2f)(0.f); \
        _Pragma("unroll") \
        for (int j = 0; j < 12; ++j) { \
          float4 v = buf[((K)&1)^1][tid + (j>>1) + (j&1)*EV_OFF]; \
          v2f vxy = (v2f){v.x, v.y}, vpm = (v2f){v.z, v.w}; \
          if (j <= 10) { const float wj=g[j];   Amu += wj*vxy; Apm += wj*vpm; } \
          if (j >= 1)  { const float wj=g[j-1]; Bmu += wj*vxy; Bpm += wj*vpm; } \
        } \
        const int c0_ = 2*tid; \
        if (c0_ < OUT_N)     acc += ssim_px(Amu.x, Amu.y, Apm.x, Apm.y); \
        if (c0_ + 1 < OUT_N) acc += ssim_px(Bmu.x, Bmu.y, Bpm.x, Bpm.y); \
      } }

    // ds_write committed -> rendezvous -> pin schedule. Counted vmcnt for the
    // prefetched global loads is left to the compiler (never drained to 0).
#define BARRIER() \
    asm volatile("s_waitcnt lgkmcnt(0)" ::: "memory"); \
    __builtin_amdgcn_s_barrier(); \
    __builtin_amdgcn_sched_barrier(0);

#define ITER(K) \
    { if ((K) >= 11) HPASS(K) \
      RINGINS((K)%12, (K)%2) \
      ISSUE_G((K)+2, (K)%2) \
      if ((K) >= 10) { VWR((K)%12, (K)&1) BARRIER() } }

    // prologue: start the pipeline with rows 0 and 1 in flight
    ISSUE(0, 0) ISSUE(1, 1)

    ITER(0)  ITER(1)  ITER(2)  ITER(3)  ITER(4)  ITER(5)
    ITER(6)  ITER(7)  ITER(8)  ITER(9)  ITER(10) ITER(11)
    ITER(12) ITER(13) ITER(14) ITER(15) ITER(16) ITER(17)
    ITER(18) ITER(19) ITER(20) ITER(21) ITER(22) ITER(23)
    ITER(24) ITER(25) ITER(26) ITER(27) ITER(28) ITER(29)
    ITER(30) ITER(31) ITER(32) ITER(33) ITER(34) ITER(35)
    ITER(36) ITER(37) ITER(38) ITER(39) ITER(40) ITER(41)
    // tail: H for output row r0+31 (V row 41 written to buf[1] at K=41)
    HPASS(42)

    // block reduction
    #pragma unroll
    for (int off = 32; off > 0; off >>= 1)
        acc += __shfl_down(acc, off, 64);
    const int lane = tid & 63, wv = tid >> 6;
    if (lane == 0) red[wv] = acc;
    __syncthreads();
    if (tid == 0)
        partial[plane * NSTRIP + strip] = red[0] + red[1] + red[2] + red[3];
}

// Deterministic final reduction: fixed traversal, double accumulation.
__global__ __launch_bounds__(256) void ssim_final(
    const float* __restrict__ partial, int n, float* __restrict__ out)
{
    __shared__ double red[256];
    double s = 0.0;
    for (int i = threadIdx.x; i < n; i += 256) s += (double)partial[i];
    red[threadIdx.x] = s;
    __syncthreads();
    for (int off = 128; off > 0; off >>= 1) {
        if (threadIdx.x < off) red[threadIdx.x] += red[threadIdx.x + off];
        __syncthreads();
    }
    if (threadIdx.x == 0) out[0] = (float)(1.0 - red[0] / (double)NPLANE);
}

extern "C" void kernel_launch(void* const* d_in, const int* in_sizes, int n_in,
                              void* d_out, int out_size, void* d_ws, size_t ws_size,
                              hipStream_t stream) {
    const float* in  = (const float*)d_in[0];
    const float* tgt = (const float*)d_in[1];
    const float* wt  = (const float*)d_in[2];
    float* out  = (float*)d_out;
    float* part = (float*)d_ws;

    dim3 grid(NSTRIP, NPLANE);   // 16 strips x 48 planes = 768 blocks
    ssim_strip<<<grid, 256, 0, stream>>>(in, tgt, wt, part);
    ssim_final<<<1, 256, 0, stream>>>(part, NSTRIP * NPLANE, out);
}